// Round 7
// baseline (163.455 us; speedup 1.0000x reference)
//
#include <hip/hip_runtime.h>

typedef float f32x4 __attribute__((ext_vector_type(4)));
typedef short short8 __attribute__((ext_vector_type(8)));
typedef unsigned int u32;
typedef unsigned short u16;
typedef u32 u32x2 __attribute__((ext_vector_type(2)));

#define CLL 0.25f                     // landmark self/neighbor coeff (deg=4)
#define CML 0.06019292654288460f      // 0.5/sqrt(69)
#define SELFM 0.014492753623188406f   // 1/69

__device__ __forceinline__ u16 f2bf(float x) {
  u32 b = __float_as_uint(x);
  return (u16)((b + 0x7FFFu + ((b >> 16) & 1u)) >> 16);
}
__device__ __forceinline__ u32 cvtpk(float a, float b) {
  u32 r;
  asm("v_cvt_pk_bf16_f32 %0, %1, %2" : "=v"(r) : "v"(a), "v"(b));
  return r;
}

// prep: (a) W mats -> bf16 MFMA B-fragments; (b) BN folded to sc/sh;
//       (c) the fixed GCN aggregation matrix A (69x69: ring + master row/col)
//           -> 12 constant bf16 A-fragments covering its 13 nonzero 16x32 tiles.
__global__ void prep(const float* __restrict__ midW, const float* __restrict__ lastW,
                     const float* __restrict__ bng, const float* __restrict__ bnb,
                     const float* __restrict__ bnm, const float* __restrict__ bnv,
                     u16* __restrict__ frag, float* __restrict__ bns,
                     u16* __restrict__ afr) {
  const int t0 = blockIdx.x * blockDim.x + threadIdx.x;
  const int stride = gridDim.x * blockDim.x;
  for (int u = t0; u < 7 * 4 * 2 * 64; u += stride) {
    const int lane = u & 63;
    const int t = u >> 6;
    const int ks = t & 1;
    const int nt = (t >> 1) & 3;
    const int l = t >> 3;  // 0..6 -> layers 1..7
    const float* W = (l < 6) ? (midW + l * 4096) : lastW;
    const int col = nt * 16 + (lane & 15);
    const int kb = ks * 32 + (lane >> 4) * 8;
    u16* dst = frag + (size_t)u * 8;
#pragma unroll
    for (int j = 0; j < 8; ++j) dst[j] = f2bf(W[(kb + j) * 64 + col]);
  }
  for (int u = t0; u < 7 * 64; u += stride) {
    const int l = u >> 6, f = u & 63;
    const float sc = (float)((double)bng[l * 64 + f] / sqrt((double)bnv[l * 64 + f] + 1e-5));
    bns[l * 128 + f] = sc;
    bns[l * 128 + 64 + f] = bnb[l * 64 + f] - bnm[l * 64 + f] * sc;
  }
  // A-frags: p -> (mt, ks). frag9 (1,2) is reused for mt=2 (identical: master col only).
  const int MTs[12] = {0, 1, 2, 4, 1, 2, 3, 4, 0, 1, 3, 4};
  const int KSs[12] = {0, 0, 0, 0, 1, 1, 1, 1, 2, 2, 2, 2};
  for (int u = t0; u < 12 * 64; u += stride) {
    const int p = u >> 6, lane = u & 63;
    const int r = MTs[p] * 16 + (lane & 15);
    const int kb = KSs[p] * 32 + ((lane >> 4) << 3);
    u16* dst = afr + (size_t)u * 8;
#pragma unroll
    for (int j = 0; j < 8; ++j) {
      const int k = kb + j;
      float v = 0.f;
      if (r < 68) {
        if (k < 68) {
          if (k == r || k == (r + 1) % 68 || k == (r + 67) % 68) v = CLL;
        } else if (k == 68) {
          v = CML;
        }
      } else if (r == 68) {
        if (k < 68) v = CML;
        else if (k == 68) v = SELFM;
      }
      dst[j] = f2bf(v);
    }
  }
}

#define SUM4(V) ((V)[0] + (V)[1] + (V)[2] + (V)[3])
#define MAX4(V) fmaxf(fmaxf((V)[0], (V)[1]), fmaxf((V)[2], (V)[3]))
#define MM(A, B, C) __builtin_amdgcn_mfma_f32_16x16x32_bf16(A, B, C, 0, 0, 0)

// MFMA1: u_tile = h @ W  (reads swizzled hb)
#define MP2(HR, MT, T)                                                   \
  {                                                                      \
    const short8 a0 = *(const short8*)&(HR)[(MT) * 1024 + ra0];          \
    const short8 a1 = *(const short8*)&(HR)[(MT) * 1024 + ra1];          \
    f32x4 acc = z4;                                                      \
    acc = MM(a0, b0, acc);                                               \
    acc = MM(a1, b1, acc);                                               \
    T = acc;                                                             \
  }

// u write: 4 consecutive nodes, col-major swizzled, one ds_write_b64
#define UWR(OFF, U)                                                      \
  {                                                                      \
    u32x2 w;                                                             \
    w.x = cvtpk(U[0], U[1]);                                             \
    w.y = cvtpk(U[2], U[3]);                                             \
    *(u32x2*)((char*)ucm + (OFF)) = w;                                   \
  }

// epilogue: relu + bn + residual, all scalar per value (no shuffles)
#define EPI2BN(AG, H, RESID)                                             \
  {                                                                      \
    _Pragma("unroll") for (int e = 0; e < 4; ++e) {                      \
      float v = fmaxf(AG[e] + bias, 0.f);                                \
      v = fmaf(v, sc, sh);                                               \
      if (RESID) v += H[e];                                              \
      H[e] = v;                                                          \
    }                                                                    \
  }

// bf16 h write into swizzled hb (addresses: 4 precomputed bases + immediates)
#define WPAIR(HW, MT, H)                                                 \
  {                                                                      \
    const u32 pa = cvtpk(H[0], H[1]);                                    \
    const u32 pb = cvtpk(H[2], H[3]);                                    \
    (HW)[(MT) * 1024 + 0 * 64 + wr0] = (u16)pa;                          \
    (HW)[(MT) * 1024 + 1 * 64 + wr1] = (u16)(pa >> 16);                  \
    (HW)[(MT) * 1024 + 2 * 64 + wr2] = (u16)pb;                          \
    (HW)[(MT) * 1024 + 3 * 64 + wr3] = (u16)(pb >> 16);                  \
  }

// MFMA2 + epilogue + h-write for all 5 M-tiles
#define AGG_EPI(HW, RESID, WRITE_H)                                      \
  {                                                                      \
    const short8 ub0 = *(const short8*)((const char*)ucm + urb);         \
    const short8 ub1 = *(const short8*)((const char*)ucm + urb + 64);    \
    const short8 ub2 = *(const short8*)((const char*)ucm + urb + 128);   \
    f32x4 ag;                                                            \
    ag = MM(F8, ub2, MM(F0, ub0, z4));                                   \
    EPI2BN(ag, h0, RESID);                                               \
    if (WRITE_H) WPAIR(HW, 0, h0);                                       \
    ag = MM(F9, ub2, MM(F4, ub1, MM(F1, ub0, z4)));                      \
    EPI2BN(ag, h1, RESID);                                               \
    if (WRITE_H) WPAIR(HW, 1, h1);                                       \
    ag = MM(F9, ub2, MM(F5, ub1, MM(F2, ub0, z4)));                      \
    EPI2BN(ag, h2, RESID);                                               \
    if (WRITE_H) WPAIR(HW, 2, h2);                                       \
    ag = MM(F10, ub2, MM(F6, ub1, z4));                                  \
    EPI2BN(ag, h3, RESID);                                               \
    if (WRITE_H) WPAIR(HW, 3, h3);                                       \
    ag = MM(F11, ub2, MM(F7, ub1, MM(F3, ub0, z4)));                     \
    EPI2BN(ag, h4, RESID);                                               \
    if (WRITE_H) WPAIR(HW, 4, h4);                                       \
  }

__launch_bounds__(256)
__global__ void gcn_fused(
    const float* __restrict__ x,
    const float* __restrict__ cfW, const float* __restrict__ cfb,
    const float* __restrict__ cmb, const float* __restrict__ clb,
    const float* __restrict__ aW1, const float* __restrict__ ab1,
    const float* __restrict__ aW2, const float* __restrict__ ab2,
    const float* __restrict__ f1W, const float* __restrict__ f1b,
    const float* __restrict__ f2W, const float* __restrict__ f2b,
    const u16* __restrict__ frag, const float* __restrict__ bns,
    const u16* __restrict__ afr,
    float* __restrict__ out) {
  // LDS: 20480 + 12288 + 1280 + 256 + 768 + 1024 = 36096 B
  __shared__ u16 hb[2][80 * 64];               // bf16 h double-buffer (row-major, swizzled)
  __shared__ __align__(16) u16 ucm[64 * 96];   // u = h@W, col-major [col][node 0..95], blk-swizzled
  __shared__ float xl4[80 * 4];                // staged x, rows 69..79 = 0
  __shared__ float mrow[64];                   // final master h
  __shared__ float gv[192];                    // readout concat [mean|max|master*att]
  __shared__ float part[256];                  // cross-wave partials (att / fc1)

  const int tid = threadIdx.x;
  const int g = blockIdx.x;
  const int lane = tid & 63;
  const int wv = tid >> 6;
  const int p15 = lane & 15;
  const int qg = lane >> 4;
  const int c = wv * 16 + p15;            // this thread's feature column
  const f32x4 z4 = {0.f, 0.f, 0.f, 0.f};

  // hb A-frag read addresses (MFMA1)
  const int rsw = (p15 & 7) << 3;
  const int ra0 = (p15 * 64 + qg * 8) ^ rsw;
  const int ra1 = (p15 * 64 + 32 + qg * 8) ^ rsw;
  // hb write bases (per R slot; + MT*1024 + R*64 immediates)
  const int cq = c ^ ((qg & 1) << 5);
  const int wr0 = qg * 256 + cq;
  const int wr1 = qg * 256 + (cq ^ 8);
  const int wr2 = qg * 256 + (cq ^ 16);
  const int wr3 = qg * 256 + (cq ^ 24);
  // ucm addresses: col stride 192 B, 16B-block index XOR-swizzled with (c&3)
  const int e3 = c & 3;
  const int q1 = qg >> 1;
  const int q0 = (qg & 1) << 3;
  const int cb = c * 192;
  const int uw0 = cb + (((0 + q1) ^ e3) << 4) + q0;   // blk 2*mt + (qg>>1)
  const int uw1 = cb + (((2 + q1) ^ e3) << 4) + q0;
  const int uw2 = cb + (((4 + q1) ^ e3) << 4) + q0;
  const int uw3 = cb + (((6 + q1) ^ e3) << 4) + q0;
  const int uw4 = cb + (((8 + q1) ^ e3) << 4) + q0;
  const int urb = cb + ((qg ^ e3) << 4);              // + 64*ks for ks=0,1,2

  // constant A-fragments (12 x short8 = 48 VGPR, loaded once)
  const u16* ap = afr + (size_t)lane * 8;
  const short8 F0 = *(const short8*)(ap);
  const short8 F1 = *(const short8*)(ap + 512);
  const short8 F2 = *(const short8*)(ap + 1024);
  const short8 F3 = *(const short8*)(ap + 1536);
  const short8 F4 = *(const short8*)(ap + 2048);
  const short8 F5 = *(const short8*)(ap + 2560);
  const short8 F6 = *(const short8*)(ap + 3072);
  const short8 F7 = *(const short8*)(ap + 3584);
  const short8 F8 = *(const short8*)(ap + 4096);
  const short8 F9 = *(const short8*)(ap + 4608);
  const short8 F10 = *(const short8*)(ap + 5120);
  const short8 F11 = *(const short8*)(ap + 5632);

  // prefetch layer-1 W fragments
  const u16* fb1 = frag + ((size_t)(0 * 4 + wv) * 2 * 64 + lane) * 8;
  short8 b0 = *(const short8*)fb1;
  short8 b1 = *(const short8*)(fb1 + 512);

  // zero ucm once (rows 80..95 must be finite forever); stage x
  {
    f32x4* ucz = (f32x4*)ucm;
#pragma unroll
    for (int it = 0; it < 3; ++it) ucz[tid + it * 256] = z4;
  }
  if (tid < 69)
    *(f32x4*)&xl4[tid * 4] = *(const f32x4*)&x[((size_t)g * 69 + tid) * 4];
  else if (tid < 80)
    *(f32x4*)&xl4[tid * 4] = z4;

  f32x4 h0, h1, h2, h3, h4;

  __syncthreads();

  // ---- layer 0: u = x @ W_first (exact fp32, K=4) -> MFMA2 agg path
  {
    const float w0 = cfW[c], w1 = cfW[64 + c], w2 = cfW[128 + c], w3 = cfW[192 + c];
    f32x4 u0, u1, u2, u3, u4;
#define L0T(MT, T)                                                          \
    { _Pragma("unroll") for (int r = 0; r < 4; ++r) {                       \
        const f32x4 xv = *(const f32x4*)&xl4[(16 * (MT) + 4 * qg + r) * 4]; \
        T[r] = fmaf(xv[0], w0, fmaf(xv[1], w1, fmaf(xv[2], w2, xv[3] * w3))); } }
    L0T(0, u0) L0T(1, u1) L0T(2, u2) L0T(3, u3) L0T(4, u4)
#undef L0T
    UWR(uw0, u0) UWR(uw1, u1) UWR(uw2, u2) UWR(uw3, u3) UWR(uw4, u4)
    const float bias = cfb[c];
    const float sc = bns[c], sh = bns[64 + c];
    u16* hw = &hb[0][0];
    AGG_EPI(hw, false, true)
  }
  __syncthreads();

  // ---- layers 1..6: MFMA1 (h@W) -> MFMA2 (A@u) -> epilogue
#pragma unroll 1
  for (int l = 1; l <= 6; ++l) {
    const u16* fbn = frag + ((size_t)(l * 4 + wv) * 2 * 64 + lane) * 8;
    const short8 nb0 = *(const short8*)fbn;
    const short8 nb1 = *(const short8*)(fbn + 512);
    const float bias = cmb[(l - 1) * 64 + c];
    const float sc = bns[l * 128 + c];
    const float sh = bns[l * 128 + 64 + c];
    const u16* hr = &hb[(l + 1) & 1][0];
    u16* hw = &hb[l & 1][0];
    f32x4 u0, u1, u2, u3, u4;
    MP2(hr, 0, u0) MP2(hr, 1, u1) MP2(hr, 2, u2) MP2(hr, 3, u3) MP2(hr, 4, u4)
    UWR(uw0, u0) UWR(uw1, u1) UWR(uw2, u2) UWR(uw3, u3) UWR(uw4, u4)
    b0 = nb0;
    b1 = nb1;
    AGG_EPI(hw, true, true)
    __syncthreads();
  }

  // ---- layer 7: MFMA1 -> MFMA2 -> relu only (no bn/resid/h-write)
  {
    const u16* hr = &hb[0][0];
    f32x4 u0, u1, u2, u3, u4;
    MP2(hr, 0, u0) MP2(hr, 1, u1) MP2(hr, 2, u2) MP2(hr, 3, u3) MP2(hr, 4, u4)
    UWR(uw0, u0) UWR(uw1, u1) UWR(uw2, u2) UWR(uw3, u3) UWR(uw4, u4)
    const float bias = clb[c];
    const float sc = 1.f, sh = 0.f;
    AGG_EPI((u16*)nullptr, false, false)
  }

  // ---- readout: per-col landmark mean/max from registers
  {
    float s = SUM4(h0) + SUM4(h1) + SUM4(h2) + SUM4(h3);
    float mx = fmaxf(fmaxf(MAX4(h0), MAX4(h1)), fmaxf(MAX4(h2), MAX4(h3)));
    if (qg == 0) {  // nodes 64..67 (valid landmarks) live in qg==0's mt=4 run
      s += SUM4(h4);
      mx = fmaxf(mx, MAX4(h4));
    }
    s += __shfl_xor(s, 16, 64);
    s += __shfl_xor(s, 32, 64);
    mx = fmaxf(mx, __shfl_xor(mx, 16, 64));
    mx = fmaxf(mx, __shfl_xor(mx, 32, 64));
    if (qg == 0) {
      gv[c] = s * (1.f / 68.f);
      gv[64 + c] = mx;
    }
    if (qg == 1) mrow[c] = h4[0];  // master h (row 68 = mt4,qg1,reg0)
  }
  __syncthreads();

  // ---- attention gate (distributed over all 4 waves)
  {
    float z = 0.f;
#pragma unroll
    for (int k = 0; k < 16; ++k)
      z = fmaf(mrow[wv * 16 + k], aW1[(wv * 16 + k) * 64 + lane], z);
    part[wv * 64 + lane] = z;
  }
  __syncthreads();
  if (tid < 64) {
    float z = part[tid] + part[64 + tid] + part[128 + tid] + part[192 + tid] + ab1[tid];
    z = fmaxf(z, 0.f);
    float pr = z * aW2[tid];
#pragma unroll
    for (int off = 32; off > 0; off >>= 1) pr += __shfl_xor(pr, off, 64);
    const float att = 1.f / (1.f + expf(-(pr + ab2[0])));
    gv[128 + tid] = mrow[tid] * att;
  }
  __syncthreads();

  // ---- fc1 partials (distributed over all 4 waves)
  {
    float a = 0.f;
#pragma unroll
    for (int i = 0; i < 48; ++i)
      a = fmaf(gv[wv * 48 + i], f1W[(wv * 48 + i) * 64 + lane], a);
    part[wv * 64 + lane] = a;
  }
  __syncthreads();
  if (tid < 64) {
    float a = part[tid] + part[64 + tid] + part[128 + tid] + part[192 + tid] + f1b[tid];
    const float y = fmaxf(a, 0.f);
    float po[7];
#pragma unroll
    for (int o = 0; o < 7; ++o) po[o] = y * f2W[tid * 7 + o];
#pragma unroll
    for (int o = 0; o < 7; ++o)
#pragma unroll
      for (int off = 32; off > 0; off >>= 1) po[o] += __shfl_xor(po[o], off, 64);
    if (tid == 0) {
#pragma unroll
      for (int o = 0; o < 7; ++o) out[(size_t)g * 7 + o] = po[o] + f2b[o];
    }
  }
}

extern "C" void kernel_launch(void* const* d_in, const int* in_sizes, int n_in,
                              void* d_out, int out_size, void* d_ws, size_t ws_size,
                              hipStream_t stream) {
  (void)in_sizes; (void)n_in; (void)ws_size;
  const float* x   = (const float*)d_in[0];
  const float* cfW = (const float*)d_in[4];
  const float* cfb = (const float*)d_in[5];
  const float* cmW = (const float*)d_in[6];
  const float* cmb = (const float*)d_in[7];
  const float* clW = (const float*)d_in[8];
  const float* clb = (const float*)d_in[9];
  const float* bng = (const float*)d_in[10];
  const float* bnb = (const float*)d_in[11];
  const float* bnm = (const float*)d_in[12];
  const float* bnv = (const float*)d_in[13];
  const float* aW1 = (const float*)d_in[14];
  const float* ab1 = (const float*)d_in[15];
  const float* aW2 = (const float*)d_in[16];
  const float* ab2 = (const float*)d_in[17];
  const float* f1W = (const float*)d_in[18];
  const float* f1b = (const float*)d_in[19];
  const float* f2W = (const float*)d_in[20];
  const float* f2b = (const float*)d_in[21];

  u16* frag  = (u16*)d_ws;                          // 57344 B (W frags)
  float* bns = (float*)((char*)d_ws + 57344);       // 3584 B (folded BN)
  u16* afr   = (u16*)((char*)d_ws + 57344 + 3584);  // 12288 B (A frags)
  const int ngraphs = out_size / 7;

  prep<<<dim3(16), dim3(256), 0, stream>>>(cmW, clW, bng, bnb, bnm, bnv, frag, bns, afr);
  gcn_fused<<<dim3(ngraphs), dim3(256), 0, stream>>>(
      x, cfW, cfb, cmb, clb, aW1, ab1, aW2, ab2, f1W, f1b, f2W, f2b,
      frag, bns, afr, (float*)d_out);
}